// Round 3
// baseline (143.805 us; speedup 1.0000x reference)
//
#include <hip/hip_runtime.h>

// Problem: hidden = tanh(x @ (Wi+Wh)^T + (bi+bh)); h_last = hidden[:, -1, :]
// x: (B,T,C) fp32; Wi,Wh: (H,C) fp32. B=16,T=4096,C=H=256.
// GEMM: M=65536, N=256, K=256. Memory-bound: ~64MB read + 67MB write.
//
// v4: one-shot blocks, 512 threads (8 waves), BM=32 rows, full N=256.
// Wave owns 32 cols: B frags (full K) = 64 VGPRs, loaded once from L2-hot Wc.
// __launch_bounds__(512,4) -> VGPR<=128 (no starvation; v3's (1024,8) cap
// forced bf out of regs -> 470 VALU instr/thread of accvgpr shuffling).
// 2 independent blocks/CU -> phase overlap across blocks, small barriers.
// Staging chunks {p, p+16} per thread -> write-side bank groups uniform
// (v3's {2p,2p+1} mapping cost exactly 1 conflict cycle per ds_write_b128).

using short8 = __attribute__((ext_vector_type(8))) short;
using f32x4  = __attribute__((ext_vector_type(4))) float;

constexpr int Bn = 16, Tn = 4096, Cn = 256, Hn = 256;
constexpr int Mn = Bn * Tn;   // 65536
constexpr int BM = 32;        // rows per block
constexpr int NBLK = Mn / BM; // 2048 blocks

// round-to-nearest-even fp32 -> bf16, two at a time, packed into one u32
__device__ inline unsigned pack2_bf16(float a, float b) {
  unsigned ua = __float_as_uint(a);
  unsigned ub = __float_as_uint(b);
  ua += 0x7fffu + ((ua >> 16) & 1u);
  ub += 0x7fffu + ((ub >> 16) & 1u);
  return (ua >> 16) | (ub & 0xffff0000u);
}

__global__ __launch_bounds__(256) void prep_kernel(
    const float* __restrict__ Wi, const float* __restrict__ bi,
    const float* __restrict__ Wh, const float* __restrict__ bh,
    unsigned short* __restrict__ Wc, float* __restrict__ bc) {
  int idx = blockIdx.x * 256 + threadIdx.x;
  float w = Wi[idx] + Wh[idx];
  unsigned u = __float_as_uint(w);
  u += 0x7fffu + ((u >> 16) & 1u);
  Wc[idx] = (unsigned short)(u >> 16);
  if (blockIdx.x == 0) bc[threadIdx.x] = bi[threadIdx.x] + bh[threadIdx.x];
}

// 512 threads = 8 waves; wave w owns output cols [32w, 32w+32).
// LDS x-tile (32x256 bf16) as 16B chunks, XOR-swizzled chunk' = chunk^(row&7).
__global__ __launch_bounds__(512, 4) void gemm_tanh_kernel(
    const float* __restrict__ x, const unsigned short* __restrict__ Wc,
    const float* __restrict__ bc, float* __restrict__ out) {
  __shared__ __align__(16) unsigned short Asm[BM * Cn];  // 16 KB

  const int tid  = threadIdx.x;
  const int lane = tid & 63;
  const int wave = tid >> 6;        // 0..7
  const int rid  = lane & 15;       // row (A) / col (B) within 16x16 tile
  const int kgrp = lane >> 4;       // 0..3: k-group of 8
  const int m0   = blockIdx.x * BM;

  // ---- staging loads first (longest latency; 64B/thread = 32KB tile)
  // thread (sr, p) covers chunks p and p+16 of row sr (chunk = 8 floats).
  const int sr = tid >> 4;          // row 0..31
  const int p  = tid & 15;          // chunk pair selector
  const float4* src = (const float4*)(x + (size_t)(m0 + sr) * Cn) + 2 * p;
  float4 a0 = src[0];
  float4 a1 = src[1];
  float4 b0 = src[32];
  float4 b1 = src[33];

  // ---- B fragments for full K=256: 2 n-tiles x 8 x short8 = 64 VGPRs
  short8 bf[2][8];
#pragma unroll
  for (int nt = 0; nt < 2; nt++) {
    int col = wave * 32 + nt * 16 + rid;
#pragma unroll
    for (int ks = 0; ks < 8; ks++)
      bf[nt][ks] = *(const short8*)&Wc[col * Cn + ks * 32 + kgrp * 8];
  }
  float bias[2];
  bias[0] = bc[wave * 32 + rid];
  bias[1] = bc[wave * 32 + 16 + rid];

  // ---- convert + stage into LDS (swizzled), one barrier
  {
    const int s = sr & 7;
    uint4 P0, P1;
    P0.x = pack2_bf16(a0.x, a0.y);
    P0.y = pack2_bf16(a0.z, a0.w);
    P0.z = pack2_bf16(a1.x, a1.y);
    P0.w = pack2_bf16(a1.z, a1.w);
    P1.x = pack2_bf16(b0.x, b0.y);
    P1.y = pack2_bf16(b0.z, b0.w);
    P1.z = pack2_bf16(b1.x, b1.y);
    P1.w = pack2_bf16(b1.z, b1.w);
    *(uint4*)&Asm[sr * Cn + ((p ^ s) << 3)] = P0;
    *(uint4*)&Asm[sr * Cn + (((p + 16) ^ s) << 3)] = P1;
  }
  __syncthreads();

  // ---- MFMA: full K unrolled, B from registers, A from LDS
  f32x4 acc[2][2];
#pragma unroll
  for (int mt = 0; mt < 2; mt++)
#pragma unroll
    for (int nt = 0; nt < 2; nt++) acc[mt][nt] = (f32x4)0.f;

#pragma unroll
  for (int ks = 0; ks < 8; ks++) {
#pragma unroll
    for (int mt = 0; mt < 2; mt++) {
      int row = mt * 16 + rid;
      short8 a = *(const short8*)
          &Asm[row * Cn + ((((ks << 2) | kgrp) ^ (rid & 7)) << 3)];
#pragma unroll
      for (int nt = 0; nt < 2; nt++)
        acc[mt][nt] = __builtin_amdgcn_mfma_f32_16x16x32_bf16(
            a, bf[nt][ks], acc[mt][nt], 0, 0, 0);
    }
  }

  // ---- epilogue: bias + tanh, store hidden (and h_last rows)
#pragma unroll
  for (int nt = 0; nt < 2; nt++) {
    int n = wave * 32 + nt * 16 + rid;
#pragma unroll
    for (int mt = 0; mt < 2; mt++) {
#pragma unroll
      for (int r = 0; r < 4; r++) {
        int m   = m0 + mt * 16 + kgrp * 4 + r;
        float v = acc[mt][nt][r] + bias[nt];
        // tanh(v) = 1 - 2/(exp(2v)+1); overflow -> 1, underflow -> -1
        float tv = 1.f - 2.f / (__expf(2.f * v) + 1.f);
        out[(size_t)m * Hn + n] = tv;
        if ((m & (Tn - 1)) == (Tn - 1))
          out[(size_t)Mn * Hn + (size_t)(m >> 12) * Hn + n] = tv;
      }
    }
  }
}

extern "C" void kernel_launch(void* const* d_in, const int* in_sizes, int n_in,
                              void* d_out, int out_size, void* d_ws,
                              size_t ws_size, hipStream_t stream) {
  (void)in_sizes; (void)n_in; (void)out_size; (void)ws_size;
  const float* x  = (const float*)d_in[0];
  const float* Wi = (const float*)d_in[1];
  const float* bi = (const float*)d_in[2];
  const float* Wh = (const float*)d_in[3];
  const float* bh = (const float*)d_in[4];
  float* out = (float*)d_out;

  unsigned short* Wc = (unsigned short*)d_ws;  // 128 KB bf16
  float* bc = (float*)((char*)d_ws + (size_t)Hn * Cn * sizeof(unsigned short));

  prep_kernel<<<(Hn * Cn) / 256, 256, 0, stream>>>(Wi, bi, Wh, bh, Wc, bc);
  gemm_tanh_kernel<<<NBLK, 512, 0, stream>>>(x, Wc, bc, out);
}

// Round 4
// 130.961 us; speedup vs baseline: 1.0981x; 1.0981x over previous
//
#include <hip/hip_runtime.h>

// Problem: hidden = tanh(x @ (Wi+Wh)^T + (bi+bh)); h_last = hidden[:, -1, :]
// x: (B,T,C) fp32; Wi,Wh: (H,C) fp32. B=16,T=4096,C=H=256.
// GEMM: M=65536, N=256, K=256. Memory-bound: ~64MB read + 67MB write -> ~21us.
//
// v5: counted-wait software pipeline. 512 blocks x 512 thr (8 waves); each
// block = 128 contiguous rows as 4 tiles of 32 through 2x16KB LDS dbuf.
// Raw barriers (s_waitcnt lgkmcnt(0); s_barrier) -- NO vmcnt drain, so
// next-next-tile x loads and epilogue stores stay in flight across every
// barrier (v4's __syncthreads drained vmcnt(0) each round -> HBM duty
// cycle ~40%). x loads issued 2 tiles (~9K cyc) ahead of consumption.
// B (weights) register/AGPR-resident per wave (32 cols x full K).

using short8 = __attribute__((ext_vector_type(8))) short;
using f32x4  = __attribute__((ext_vector_type(4))) float;

constexpr int Bn = 16, Tn = 4096, Cn = 256, Hn = 256;
constexpr int Mn   = Bn * Tn;          // 65536
constexpr int BM   = 32;               // rows per tile
constexpr int TPB  = 4;                // tiles per block (pipeline depth)
constexpr int NBLK = Mn / (BM * TPB);  // 512 blocks -> 2 per CU

// raw workgroup barrier: LDS visibility only, vmem stays in flight
#define PIPE_BARRIER() asm volatile("s_waitcnt lgkmcnt(0)\n\ts_barrier" ::: "memory")

// round-to-nearest-even fp32 -> bf16, two at a time, packed into one u32
__device__ inline unsigned pack2_bf16(float a, float b) {
  unsigned ua = __float_as_uint(a);
  unsigned ub = __float_as_uint(b);
  ua += 0x7fffu + ((ua >> 16) & 1u);
  ub += 0x7fffu + ((ub >> 16) & 1u);
  return (ua >> 16) | (ub & 0xffff0000u);
}

__global__ __launch_bounds__(256) void prep_kernel(
    const float* __restrict__ Wi, const float* __restrict__ bi,
    const float* __restrict__ Wh, const float* __restrict__ bh,
    unsigned short* __restrict__ Wc, float* __restrict__ bc) {
  int idx = blockIdx.x * 256 + threadIdx.x;
  float w = Wi[idx] + Wh[idx];
  unsigned u = __float_as_uint(w);
  u += 0x7fffu + ((u >> 16) & 1u);
  Wc[idx] = (unsigned short)(u >> 16);
  if (blockIdx.x == 0) bc[threadIdx.x] = bi[threadIdx.x] + bh[threadIdx.x];
}

// 512 threads = 8 waves; wave w owns output cols [32w, 32w+32).
// LDS x-tile (32x256 bf16) as 16B chunks, XOR-swizzled chunk' = chunk^(row&7);
// staging thread covers chunks {p, p+16} -> write side spans all bank groups.
__global__ __launch_bounds__(512, 4) void gemm_tanh_kernel(
    const float* __restrict__ x, const unsigned short* __restrict__ Wc,
    const float* __restrict__ bc, float* __restrict__ out) {
  __shared__ __align__(16) unsigned short Asm[2][BM * Cn];  // 2 x 16 KB

  const int tid  = threadIdx.x;
  const int lane = tid & 63;
  const int wave = tid >> 6;        // 0..7
  const int rid  = lane & 15;       // row (A) / col (B) within 16x16 tile
  const int kgrp = lane >> 4;       // 0..3: k-group of 8
  const int mBase = blockIdx.x * (BM * TPB);

  // staging role: thread (sr, p) covers 16B chunks p and p+16 of row sr
  const int sr = tid >> 4;          // row 0..31
  const int p  = tid & 15;
  const int s  = sr & 7;

  // ---- pipeline prologue: issue x loads for tiles 0 and 1 first (HBM
  // critical path), then weight fragments (L2-hot).
  float4 xr[2][4];
#pragma unroll
  for (int t = 0; t < 2; t++) {
    const float4* src =
        (const float4*)(x + (size_t)(mBase + t * BM + sr) * Cn) + 2 * p;
    xr[t][0] = src[0];
    xr[t][1] = src[1];
    xr[t][2] = src[32];
    xr[t][3] = src[33];
  }

  // B fragments for full K=256: 2 n-tiles x 8 x short8 (lands in AGPRs,
  // MFMA reads them directly on gfx950's unified file)
  short8 bf[2][8];
#pragma unroll
  for (int nt = 0; nt < 2; nt++) {
    int col = wave * 32 + nt * 16 + rid;
#pragma unroll
    for (int ks = 0; ks < 8; ks++)
      bf[nt][ks] = *(const short8*)&Wc[col * Cn + ks * 32 + kgrp * 8];
  }
  float bias[2];
  bias[0] = bc[wave * 32 + rid];
  bias[1] = bc[wave * 32 + 16 + rid];

  // stage tile 0 into buf 0 (compiler inserts counted vmcnt for xr[0])
  {
    uint4 P0, P1;
    P0.x = pack2_bf16(xr[0][0].x, xr[0][0].y);
    P0.y = pack2_bf16(xr[0][0].z, xr[0][0].w);
    P0.z = pack2_bf16(xr[0][1].x, xr[0][1].y);
    P0.w = pack2_bf16(xr[0][1].z, xr[0][1].w);
    P1.x = pack2_bf16(xr[0][2].x, xr[0][2].y);
    P1.y = pack2_bf16(xr[0][2].z, xr[0][2].w);
    P1.z = pack2_bf16(xr[0][3].x, xr[0][3].y);
    P1.w = pack2_bf16(xr[0][3].z, xr[0][3].w);
    *(uint4*)&Asm[0][sr * Cn + ((p ^ s) << 3)] = P0;
    *(uint4*)&Asm[0][sr * Cn + (((p + 16) ^ s) << 3)] = P1;
  }
  PIPE_BARRIER();

  // ---- main pipeline: iter t computes tile t from buf (t&1), writes tile
  // t+1 into buf (t+1)&1, and has tile t+2's loads in flight the whole time.
#pragma unroll
  for (int t = 0; t < TPB; t++) {
    const int cur = t & 1;

    // issue x loads for tile t+2 into the reg set freed by tile t's staging
    if (t + 2 < TPB) {
      const float4* src =
          (const float4*)(x + (size_t)(mBase + (t + 2) * BM + sr) * Cn) + 2 * p;
      xr[cur][0] = src[0];
      xr[cur][1] = src[1];
      xr[cur][2] = src[32];
      xr[cur][3] = src[33];
    }

    // MFMA: tile t, full K unrolled, B from registers/AGPRs
    f32x4 acc[2][2];
#pragma unroll
    for (int mt = 0; mt < 2; mt++)
#pragma unroll
      for (int nt = 0; nt < 2; nt++) acc[mt][nt] = (f32x4)0.f;

#pragma unroll
    for (int ks = 0; ks < 8; ks++) {
#pragma unroll
      for (int mt = 0; mt < 2; mt++) {
        int row = mt * 16 + rid;
        short8 a = *(const short8*)
            &Asm[cur][row * Cn + ((((ks << 2) | kgrp) ^ (rid & 7)) << 3)];
#pragma unroll
        for (int nt = 0; nt < 2; nt++)
          acc[mt][nt] = __builtin_amdgcn_mfma_f32_16x16x32_bf16(
              a, bf[nt][ks], acc[mt][nt], 0, 0, 0);
      }
    }

    // stage tile t+1 (loads issued 1.5 iters ago -> counted vmcnt, no stall)
    if (t + 1 < TPB) {
      const float4* r = xr[cur ^ 1];
      uint4 P0, P1;
      P0.x = pack2_bf16(r[0].x, r[0].y);
      P0.y = pack2_bf16(r[0].z, r[0].w);
      P0.z = pack2_bf16(r[1].x, r[1].y);
      P0.w = pack2_bf16(r[1].z, r[1].w);
      P1.x = pack2_bf16(r[2].x, r[2].y);
      P1.y = pack2_bf16(r[2].z, r[2].w);
      P1.z = pack2_bf16(r[3].x, r[3].y);
      P1.w = pack2_bf16(r[3].z, r[3].w);
      *(uint4*)&Asm[cur ^ 1][sr * Cn + ((p ^ s) << 3)] = P0;
      *(uint4*)&Asm[cur ^ 1][sr * Cn + (((p + 16) ^ s) << 3)] = P1;
    }

    // epilogue tile t: bias + tanh, store (stores ride across the barrier)
#pragma unroll
    for (int nt = 0; nt < 2; nt++) {
      int n = wave * 32 + nt * 16 + rid;
#pragma unroll
      for (int mt = 0; mt < 2; mt++) {
#pragma unroll
        for (int r = 0; r < 4; r++) {
          int m   = mBase + t * BM + mt * 16 + kgrp * 4 + r;
          float v = acc[mt][nt][r] + bias[nt];
          // tanh(v) = 1 - 2/(exp(2v)+1); overflow -> 1, underflow -> -1
          float tv = 1.f - 2.f / (__expf(2.f * v) + 1.f);
          out[(size_t)m * Hn + n] = tv;
          if ((m & (Tn - 1)) == (Tn - 1))
            out[(size_t)Mn * Hn + (size_t)(m >> 12) * Hn + n] = tv;
        }
      }
    }

    if (t + 1 < TPB) PIPE_BARRIER();
  }
}

extern "C" void kernel_launch(void* const* d_in, const int* in_sizes, int n_in,
                              void* d_out, int out_size, void* d_ws,
                              size_t ws_size, hipStream_t stream) {
  (void)in_sizes; (void)n_in; (void)out_size; (void)ws_size;
  const float* x  = (const float*)d_in[0];
  const float* Wi = (const float*)d_in[1];
  const float* bi = (const float*)d_in[2];
  const float* Wh = (const float*)d_in[3];
  const float* bh = (const float*)d_in[4];
  float* out = (float*)d_out;

  unsigned short* Wc = (unsigned short*)d_ws;  // 128 KB bf16
  float* bc = (float*)((char*)d_ws + (size_t)Hn * Cn * sizeof(unsigned short));

  prep_kernel<<<(Hn * Cn) / 256, 256, 0, stream>>>(Wi, bi, Wh, bh, Wc, bc);
  gemm_tanh_kernel<<<NBLK, 512, 0, stream>>>(x, Wc, bc, out);
}